// Round 2
// baseline (6660.006 us; speedup 1.0000x reference)
//
#include <hip/hip_runtime.h>
#include <hip/hip_cooperative_groups.h>
#include <cmath>
#include <type_traits>

namespace cg = cooperative_groups;

// ChEst: shared-weight Elman RNN, H=8192, 64 steps.
//   U = x @ W_ih^T + b   (one f16-MFMA GEMM, written into d_out)
//   h_t = tanh(U[t] + W_hh @ h_{t-1})
// Persistent cooperative kernel holds ALL of W_hh on-chip:
//   per wave (2048 waves): rows +0..+2 in VGPRs (192), row +3 in LDS (16 KiB).
//   Per step: 16 KiB h broadcast read + one grid.sync. Zero W traffic.

#define HDIM 8192
#define NSTEP 64

typedef _Float16 f16;
typedef _Float16 f16x2 __attribute__((ext_vector_type(2)));
typedef _Float16 f16x4 __attribute__((ext_vector_type(4)));
typedef _Float16 f16x8 __attribute__((ext_vector_type(8)));
typedef __fp16 fp16x2_raw __attribute__((ext_vector_type(2)));
typedef float f32x4 __attribute__((ext_vector_type(4)));

#if defined(__has_builtin)
#if __has_builtin(__builtin_amdgcn_fdot2)
#define HAS_FDOT2 1
#endif
#endif

__device__ __forceinline__ f16x2 pkrtz(float a, float b) {
  fp16x2_raw r = __builtin_amdgcn_cvt_pkrtz(a, b);
  return __builtin_bit_cast(f16x2, r);
}

__device__ __forceinline__ float dot2acc(f16 a0, f16 a1, f16 b0, f16 b1, float c) {
#ifdef HAS_FDOT2
  f16x2 a = {a0, a1}, b = {b0, b1};
  return __builtin_amdgcn_fdot2(a, b, c, false);
#else
  return c + (float)a0 * (float)b0 + (float)a1 * (float)b1;
#endif
}

__device__ __forceinline__ float dot8(f16x8 a, f16x8 b, float c) {
  c = dot2acc(a[0], a[1], b[0], b[1], c);
  c = dot2acc(a[2], a[3], b[2], b[3], c);
  c = dot2acc(a[4], a[5], b[4], b[5], c);
  c = dot2acc(a[6], a[7], b[6], b[7], c);
  return c;
}

__device__ __forceinline__ f16x8 cvt8(const float* __restrict__ p) {
  f32x4 a0 = *(const f32x4*)p;
  f32x4 a1 = *(const f32x4*)(p + 4);
  f16x2 p0 = pkrtz(a0[0], a0[1]);
  f16x2 p1 = pkrtz(a0[2], a0[3]);
  f16x2 p2 = pkrtz(a1[0], a1[1]);
  f16x2 p3 = pkrtz(a1[2], a1[3]);
  return (f16x8){p0[0], p0[1], p1[0], p1[1], p2[0], p2[1], p3[0], p3[1]};
}

// ---------------- fp32 -> fp16 convert (grid-stride, vectorized) -------------
__global__ void cvt_f16_kernel(const float* __restrict__ src,
                               f16* __restrict__ dst, int n4) {
  int idx = blockIdx.x * blockDim.x + threadIdx.x;
  int stride = gridDim.x * blockDim.x;
  for (int i = idx; i < n4; i += stride) {
    f32x4 v = ((const f32x4*)src)[i];
    f16x4 h;
    h[0] = (f16)v[0]; h[1] = (f16)v[1]; h[2] = (f16)v[2]; h[3] = (f16)v[3];
    ((f16x4*)dst)[i] = h;
  }
}

// ---------------- Phase 1: U = x @ W_ih^T + b  (into d_out) ------------------
template <bool XF16>
__global__ __launch_bounds__(256) void gemm_u_kernel(
    const float* __restrict__ x, const f16* __restrict__ x16,
    const float* __restrict__ Wih, const float* __restrict__ b,
    float* __restrict__ out) {
  const int wave = threadIdx.x >> 6;
  const int lane = threadIdx.x & 63;
  const int r = lane & 15, q = lane >> 4;
  const int n0 = blockIdx.x * 16;
  const int m0 = wave * 16;
  const float* wrow = Wih + (size_t)(n0 + r) * HDIM;
  f32x4 acc = {0.f, 0.f, 0.f, 0.f};
#pragma unroll 2
  for (int k0 = 0; k0 < HDIM; k0 += 32) {
    const int kb = k0 + q * 8;
    f16x8 fa;
    if constexpr (XF16) {
      fa = *(const f16x8*)(x16 + (size_t)(m0 + r) * HDIM + kb);
    } else {
      f32x4 a0 = *(const f32x4*)(x + (size_t)(m0 + r) * HDIM + kb);
      f32x4 a1 = *(const f32x4*)(x + (size_t)(m0 + r) * HDIM + kb + 4);
      f16x2 p0 = pkrtz(a0[0], a0[1]);
      f16x2 p1 = pkrtz(a0[2], a0[3]);
      f16x2 p2 = pkrtz(a1[0], a1[1]);
      f16x2 p3 = pkrtz(a1[2], a1[3]);
      fa = (f16x8){p0[0], p0[1], p1[0], p1[1], p2[0], p2[1], p3[0], p3[1]};
    }
    f32x4 b0 = *(const f32x4*)(wrow + kb);
    f32x4 b1 = *(const f32x4*)(wrow + kb + 4);
    f16x2 q0 = pkrtz(b0[0], b0[1]);
    f16x2 q1 = pkrtz(b0[2], b0[3]);
    f16x2 q2 = pkrtz(b1[0], b1[1]);
    f16x2 q3 = pkrtz(b1[2], b1[3]);
    f16x8 fb = {q0[0], q0[1], q1[0], q1[1], q2[0], q2[1], q3[0], q3[1]};
    acc = __builtin_amdgcn_mfma_f32_16x16x32_f16(fa, fb, acc, 0, 0, 0);
  }
  const float bv = b[n0 + r];
#pragma unroll
  for (int i = 0; i < 4; i++) {
    out[(size_t)(m0 + q * 4 + i) * HDIM + n0 + r] = acc[i] + bv;
  }
}

// ---------------- persistent cooperative RNN (all 64 steps) ------------------
// grid = 512 blocks x 256 thr (4 waves). Global wave gw owns rows 4*gw..+3:
// rows +0,+1,+2 pinned in VGPRs (48 x f16x8 = 192 VGPR), row +3 in LDS.
// h kept as fp16 in a 2x8192 double buffer in d_ws; one grid.sync per step.
// Occupancy: 64 KiB LDS + 256 VGPR cap -> exactly 2 blocks/CU, 512 = 2*256 CU.
__global__ __launch_bounds__(256, 2) void rnn_persistent(
    const float* __restrict__ Whh, float* __restrict__ out,
    f16* __restrict__ h16) {
  __shared__ f16 wlds[4][HDIM];  // 64 KiB
  const int wave = threadIdx.x >> 6;
  const int lane = threadIdx.x & 63;
  const int row0 = (blockIdx.x * 4 + wave) * 4;
  const int lb = lane * 8;

  // ---- prologue: load + convert W_hh rows once (fp32 -> fp16) ----
  f16x8 w0[16], w1[16], w2[16];
#pragma unroll
  for (int i = 0; i < 16; i++) {
    const int kb = i * 512 + lb;
    const float* p = Whh + (size_t)row0 * HDIM + kb;
    w0[i] = cvt8(p);
    w1[i] = cvt8(p + HDIM);
    w2[i] = cvt8(p + 2 * HDIM);
    *(f16x8*)&wlds[wave][kb] = cvt8(p + 3 * HDIM);  // wave-private: no barrier
  }

  // ---- step 0: h_0 = tanh(U[0]) (h_init = 0) ----
  if (lane < 4) {
    float v = tanhf(out[row0 + lane]);
    h16[row0 + lane] = (f16)v;  // buffer 0 first: readers wait on this
    out[row0 + lane] = v;
  }
  __threadfence();
  cg::this_grid().sync();

  for (int t = 1; t < NSTEP; t++) {
    const f16* hp = h16 + ((t - 1) & 1) * HDIM;
    // Prefetch U[t] for this wave's rows before the dot loop (hides latency).
    float* op = out + (size_t)t * HDIM + row0;
    float u0, u1, u2, u3;
    if (lane == 0) { u0 = op[0]; u1 = op[1]; u2 = op[2]; u3 = op[3]; }
    float a0 = 0.f, a1 = 0.f, a2 = 0.f, a3 = 0.f;
#pragma unroll
    for (int i = 0; i < 16; i++) {
      const int kb = i * 512 + lb;
      f16x8 h = *(const f16x8*)(hp + kb);           // broadcast, L1-hit
      f16x8 p3 = *(const f16x8*)&wlds[wave][kb];    // pinned row, ds_read_b128
      a0 = dot8(w0[i], h, a0);
      a1 = dot8(w1[i], h, a1);
      a2 = dot8(w2[i], h, a2);
      a3 = dot8(p3, h, a3);
    }
#pragma unroll
    for (int off = 32; off >= 1; off >>= 1) {
      a0 += __shfl_down(a0, off, 64);
      a1 += __shfl_down(a1, off, 64);
      a2 += __shfl_down(a2, off, 64);
      a3 += __shfl_down(a3, off, 64);
    }
    if (lane == 0) {
      float v0 = tanhf(u0 + a0);
      float v1 = tanhf(u1 + a1);
      float v2 = tanhf(u2 + a2);
      float v3 = tanhf(u3 + a3);
      f16x4 hh;
      hh[0] = (f16)v0; hh[1] = (f16)v1; hh[2] = (f16)v2; hh[3] = (f16)v3;
      *(f16x4*)(h16 + (t & 1) * HDIM + row0) = hh;  // release chain first
      op[0] = v0; op[1] = v1; op[2] = v2; op[3] = v3;
    }
    if (t != NSTEP - 1) {
      __threadfence();
      cg::this_grid().sync();
    }
  }
}

// ---------------- fallback path (previous verified kernels) ------------------
__global__ void step0_kernel(float* __restrict__ out) {
  int i = blockIdx.x * blockDim.x + threadIdx.x;
  out[i] = tanhf(out[i]);
}

template <bool WF16>
__global__ __launch_bounds__(1024) void step_kernel(const void* __restrict__ Wv,
                                                    float* __restrict__ out,
                                                    int t) {
  __shared__ typename std::conditional<WF16, f16, float>::type hs[HDIM];
  const float* hprev = out + (size_t)(t - 1) * HDIM;
  {
    const f32x4* hp4 = (const f32x4*)hprev;
    const int tid = threadIdx.x;
#pragma unroll
    for (int i = 0; i < HDIM / 4 / 1024; i++) {
      const int idx = i * 1024 + tid;
      f32x4 v = hp4[idx];
      if constexpr (WF16) {
        f16x4 hh;
        hh[0] = (f16)v[0]; hh[1] = (f16)v[1];
        hh[2] = (f16)v[2]; hh[3] = (f16)v[3];
        *(f16x4*)&hs[idx * 4] = hh;
      } else {
        *(f32x4*)&hs[idx * 4] = v;
      }
    }
  }
  __syncthreads();

  const int wave = threadIdx.x >> 6;
  const int lane = threadIdx.x & 63;
  const int j = blockIdx.x * 16 + wave;
  float acc = 0.f;

  if constexpr (WF16) {
    const f16* wrow = (const f16*)Wv + (size_t)j * HDIM;
#pragma unroll 4
    for (int it = 0; it < 16; it++) {
      const int kb = it * 512 + lane * 8;
      f16x8 w = *(const f16x8*)(wrow + kb);
      f16x8 h = *(const f16x8*)&hs[kb];
      acc = dot2acc(w[0], w[1], h[0], h[1], acc);
      acc = dot2acc(w[2], w[3], h[2], h[3], acc);
      acc = dot2acc(w[4], w[5], h[4], h[5], acc);
      acc = dot2acc(w[6], w[7], h[6], h[7], acc);
    }
  } else {
    const float* wrow = (const float*)Wv + (size_t)j * HDIM;
#pragma unroll 4
    for (int it = 0; it < 16; it++) {
      const int kb = it * 512 + lane * 8;
      f32x4 w0 = *(const f32x4*)(wrow + kb);
      f32x4 w1 = *(const f32x4*)(wrow + kb + 4);
      const float* hp = (const float*)&hs[kb];
      acc += w0[0] * hp[0] + w0[1] * hp[1] + w0[2] * hp[2] + w0[3] * hp[3];
      acc += w1[0] * hp[4] + w1[1] * hp[5] + w1[2] * hp[6] + w1[3] * hp[7];
    }
  }
#pragma unroll
  for (int off = 32; off >= 1; off >>= 1) acc += __shfl_down(acc, off, 64);
  if (lane == 0) {
    const float u = out[(size_t)t * HDIM + j];
    out[(size_t)t * HDIM + j] = tanhf(u + acc);
  }
}

// -----------------------------------------------------------------------------
extern "C" void kernel_launch(void* const* d_in, const int* in_sizes, int n_in,
                              void* d_out, int out_size, void* d_ws,
                              size_t ws_size, hipStream_t stream) {
  const float* x = (const float*)d_in[0];
  const float* Wih = (const float*)d_in[1];
  const float* Whh = (const float*)d_in[2];
  const float* b = (const float*)d_in[3];
  float* out = (float*)d_out;

  const size_t needH = (size_t)2 * HDIM * sizeof(f16);          // 32 KiB
  const size_t needX = (size_t)NSTEP * HDIM * sizeof(f16);      // 1 MiB
  const size_t needW = (size_t)HDIM * HDIM * sizeof(f16);       // 128 MiB

  if (ws_size >= needH + needX) {
    f16* h16 = (f16*)d_ws;
    f16* x16 = (f16*)((char*)d_ws + needH);
    cvt_f16_kernel<<<64, 256, 0, stream>>>(x, x16, NSTEP * HDIM / 4);
    gemm_u_kernel<true><<<HDIM / 16, 256, 0, stream>>>(x, x16, Wih, b, out);

    void* args[] = {(void*)&Whh, (void*)&out, (void*)&h16};
    hipError_t rc = hipLaunchCooperativeKernel(
        (void*)rnn_persistent, dim3(512), dim3(256), args, 0, stream);
    if (rc == hipSuccess) return;
    (void)hipGetLastError();  // clear error state, take fallback path

    step0_kernel<<<HDIM / 256, 256, 0, stream>>>(out);
    if (ws_size >= needH + needX + needW) {
      f16* w16 = (f16*)((char*)d_ws + needH + needX);
      cvt_f16_kernel<<<4096, 256, 0, stream>>>(Whh, w16, HDIM * HDIM / 4);
      for (int t = 1; t < NSTEP; t++)
        step_kernel<true><<<HDIM / 16, 1024, 0, stream>>>((const void*)w16, out, t);
    } else {
      for (int t = 1; t < NSTEP; t++)
        step_kernel<false><<<HDIM / 16, 1024, 0, stream>>>((const void*)Whh, out, t);
    }
    return;
  }

  // tiny-workspace fallback: all-fp32 path
  gemm_u_kernel<false><<<HDIM / 16, 256, 0, stream>>>(x, nullptr, Wih, b, out);
  step0_kernel<<<HDIM / 256, 256, 0, stream>>>(out);
  for (int t = 1; t < NSTEP; t++)
    step_kernel<false><<<HDIM / 16, 1024, 0, stream>>>((const void*)Whh, out, t);
}

// Round 4
// 5323.289 us; speedup vs baseline: 1.2511x; 1.2511x over previous
//
#include <hip/hip_runtime.h>
#include <cmath>
#include <type_traits>

// ChEst: shared-weight Elman RNN, H=8192, 64 steps.
//   U = x @ W_ih^T + b   (one f16-MFMA GEMM, written into d_out)
//   h_t = tanh(U[t] + W_hh @ h_{t-1})
// Persistent kernel holds ALL of W_hh on-chip:
//   per wave (2048 waves): rows +0..+2 in VGPRs (192), row +3 in LDS (16 KiB).
// R2 fix: cg::grid.sync() (external OCKL call) capped VGPRs at 128 -> all W
// arrays spilled to scratch (6.1 ms, VALUBusy 1.3%). Replaced with a fully
// inlined flag/release grid barrier + amdgpu_waves_per_eu(2,2).
// R3 fix: acquire fence in block 0 between flag-poll and release store
// (formal release-chain transitivity; hw-safe either way).

#define HDIM 8192
#define NSTEP 64
#define NBLK 512

typedef _Float16 f16;
typedef _Float16 f16x2 __attribute__((ext_vector_type(2)));
typedef _Float16 f16x4 __attribute__((ext_vector_type(4)));
typedef _Float16 f16x8 __attribute__((ext_vector_type(8)));
typedef __fp16 fp16x2_raw __attribute__((ext_vector_type(2)));
typedef float f32x4 __attribute__((ext_vector_type(4)));

#if defined(__has_builtin)
#if __has_builtin(__builtin_amdgcn_fdot2)
#define HAS_FDOT2 1
#endif
#endif

__device__ __forceinline__ f16x2 pkrtz(float a, float b) {
  fp16x2_raw r = __builtin_amdgcn_cvt_pkrtz(a, b);
  return __builtin_bit_cast(f16x2, r);
}

__device__ __forceinline__ float dot2acc(f16 a0, f16 a1, f16 b0, f16 b1, float c) {
#ifdef HAS_FDOT2
  f16x2 a = {a0, a1}, b = {b0, b1};
  return __builtin_amdgcn_fdot2(a, b, c, false);
#else
  return c + (float)a0 * (float)b0 + (float)a1 * (float)b1;
#endif
}

__device__ __forceinline__ float dot8(f16x8 a, f16x8 b, float c) {
  c = dot2acc(a[0], a[1], b[0], b[1], c);
  c = dot2acc(a[2], a[3], b[2], b[3], c);
  c = dot2acc(a[4], a[5], b[4], b[5], c);
  c = dot2acc(a[6], a[7], b[6], b[7], c);
  return c;
}

__device__ __forceinline__ f16x8 cvt8(const float* __restrict__ p) {
  f32x4 a0 = *(const f32x4*)p;
  f32x4 a1 = *(const f32x4*)(p + 4);
  f16x2 p0 = pkrtz(a0[0], a0[1]);
  f16x2 p1 = pkrtz(a0[2], a0[3]);
  f16x2 p2 = pkrtz(a1[0], a1[1]);
  f16x2 p3 = pkrtz(a1[2], a1[3]);
  return (f16x8){p0[0], p0[1], p1[0], p1[1], p2[0], p2[1], p3[0], p3[1]};
}

// ---------------- inlined grid barrier (no external calls) -------------------
// flags[b*32]: arrival epoch of block b (128 B stride). release[0]: go epoch.
// Block 0 polls all flags (2 per thread), then bumps release. Monotonic epochs,
// zero-init via hipMemsetAsync each launch -> no reset race, no ABA.
__device__ __forceinline__ void gbar(unsigned* __restrict__ flags,
                                     unsigned* __restrict__ release,
                                     unsigned e) {
  __threadfence();   // release: make this thread's h16 stores device-visible
  __syncthreads();   // whole block arrived + fenced
  const int tid = threadIdx.x;
  if (blockIdx.x == 0) {
    if (tid == 0)
      __hip_atomic_store(&flags[0], e, __ATOMIC_RELEASE, __HIP_MEMORY_SCOPE_AGENT);
    for (int i = tid; i < NBLK; i += 256) {
      while (__hip_atomic_load(&flags[i * 32], __ATOMIC_RELAXED,
                               __HIP_MEMORY_SCOPE_AGENT) < e)
        __builtin_amdgcn_s_sleep(1);
    }
    __threadfence();  // acquire: order release store after observed arrivals
    __syncthreads();
    if (tid == 0)
      __hip_atomic_store(release, e, __ATOMIC_RELEASE, __HIP_MEMORY_SCOPE_AGENT);
  } else {
    if (tid == 0) {
      __hip_atomic_store(&flags[blockIdx.x * 32], e, __ATOMIC_RELEASE,
                         __HIP_MEMORY_SCOPE_AGENT);
      while (__hip_atomic_load(release, __ATOMIC_RELAXED,
                               __HIP_MEMORY_SCOPE_AGENT) < e)
        __builtin_amdgcn_s_sleep(1);
    }
    __syncthreads();
  }
  __threadfence();   // acquire side: drop stale cached h16 lines
}

// ---------------- fp32 -> fp16 convert (grid-stride, vectorized) -------------
__global__ void cvt_f16_kernel(const float* __restrict__ src,
                               f16* __restrict__ dst, int n4) {
  int idx = blockIdx.x * blockDim.x + threadIdx.x;
  int stride = gridDim.x * blockDim.x;
  for (int i = idx; i < n4; i += stride) {
    f32x4 v = ((const f32x4*)src)[i];
    f16x4 h;
    h[0] = (f16)v[0]; h[1] = (f16)v[1]; h[2] = (f16)v[2]; h[3] = (f16)v[3];
    ((f16x4*)dst)[i] = h;
  }
}

// ---------------- Phase 1: U = x @ W_ih^T + b  (into d_out) ------------------
template <bool XF16>
__global__ __launch_bounds__(256) void gemm_u_kernel(
    const float* __restrict__ x, const f16* __restrict__ x16,
    const float* __restrict__ Wih, const float* __restrict__ b,
    float* __restrict__ out) {
  const int wave = threadIdx.x >> 6;
  const int lane = threadIdx.x & 63;
  const int r = lane & 15, q = lane >> 4;
  const int n0 = blockIdx.x * 16;
  const int m0 = wave * 16;
  const float* wrow = Wih + (size_t)(n0 + r) * HDIM;
  f32x4 acc = {0.f, 0.f, 0.f, 0.f};
#pragma unroll 2
  for (int k0 = 0; k0 < HDIM; k0 += 32) {
    const int kb = k0 + q * 8;
    f16x8 fa;
    if constexpr (XF16) {
      fa = *(const f16x8*)(x16 + (size_t)(m0 + r) * HDIM + kb);
    } else {
      f32x4 a0 = *(const f32x4*)(x + (size_t)(m0 + r) * HDIM + kb);
      f32x4 a1 = *(const f32x4*)(x + (size_t)(m0 + r) * HDIM + kb + 4);
      f16x2 p0 = pkrtz(a0[0], a0[1]);
      f16x2 p1 = pkrtz(a0[2], a0[3]);
      f16x2 p2 = pkrtz(a1[0], a1[1]);
      f16x2 p3 = pkrtz(a1[2], a1[3]);
      fa = (f16x8){p0[0], p0[1], p1[0], p1[1], p2[0], p2[1], p3[0], p3[1]};
    }
    f32x4 b0 = *(const f32x4*)(wrow + kb);
    f32x4 b1 = *(const f32x4*)(wrow + kb + 4);
    f16x2 q0 = pkrtz(b0[0], b0[1]);
    f16x2 q1 = pkrtz(b0[2], b0[3]);
    f16x2 q2 = pkrtz(b1[0], b1[1]);
    f16x2 q3 = pkrtz(b1[2], b1[3]);
    f16x8 fb = {q0[0], q0[1], q1[0], q1[1], q2[0], q2[1], q3[0], q3[1]};
    acc = __builtin_amdgcn_mfma_f32_16x16x32_f16(fa, fb, acc, 0, 0, 0);
  }
  const float bv = b[n0 + r];
#pragma unroll
  for (int i = 0; i < 4; i++) {
    out[(size_t)(m0 + q * 4 + i) * HDIM + n0 + r] = acc[i] + bv;
  }
}

// ---------------- persistent RNN (all 64 steps, manual grid barrier) ---------
// grid = 512 blocks x 256 thr (4 waves). Global wave gw owns rows 4*gw..+3:
// rows +0,+1,+2 pinned in VGPRs (48 x f16x8 = 192 VGPR), row +3 in LDS.
// Occupancy: 64 KiB LDS -> 2 blocks/CU; waves_per_eu(2,2) -> 256-VGPR budget.
__global__ __attribute__((amdgpu_flat_work_group_size(256, 256)))
__attribute__((amdgpu_waves_per_eu(2, 2))) void rnn_persistent(
    const float* __restrict__ Whh, float* __restrict__ out,
    f16* __restrict__ h16, unsigned* __restrict__ flags,
    unsigned* __restrict__ release) {
  __shared__ f16 wlds[4][HDIM];  // 64 KiB
  const int wave = threadIdx.x >> 6;
  const int lane = threadIdx.x & 63;
  const int row0 = (blockIdx.x * 4 + wave) * 4;
  const int lb = lane * 8;

  // ---- prologue: load + convert W_hh rows once (fp32 -> fp16) ----
  f16x8 w0[16], w1[16], w2[16];
#pragma unroll
  for (int i = 0; i < 16; i++) {
    const int kb = i * 512 + lb;
    const float* p = Whh + (size_t)row0 * HDIM + kb;
    w0[i] = cvt8(p);
    w1[i] = cvt8(p + HDIM);
    w2[i] = cvt8(p + 2 * HDIM);
    *(f16x8*)&wlds[wave][kb] = cvt8(p + 3 * HDIM);  // wave-private: no barrier
  }

  // ---- step 0: h_0 = tanh(U[0]) (h_init = 0) ----
  if (lane < 4) {
    float v = tanhf(out[row0 + lane]);
    h16[row0 + lane] = (f16)v;  // buffer 0 first: readers wait on this
    out[row0 + lane] = v;
  }
  gbar(flags, release, 1u);

  for (int t = 1; t < NSTEP; t++) {
    const f16* hp = h16 + ((t - 1) & 1) * HDIM;
    // Prefetch U[t] for this wave's rows before the dot loop (hides latency).
    float* op = out + (size_t)t * HDIM + row0;
    float u0, u1, u2, u3;
    if (lane == 0) { u0 = op[0]; u1 = op[1]; u2 = op[2]; u3 = op[3]; }
    float a0 = 0.f, a1 = 0.f, a2 = 0.f, a3 = 0.f;
#pragma unroll
    for (int i = 0; i < 16; i++) {
      const int kb = i * 512 + lb;
      f16x8 h = *(const f16x8*)(hp + kb);           // broadcast, L1-hit
      f16x8 p3 = *(const f16x8*)&wlds[wave][kb];    // pinned row, ds_read_b128
      a0 = dot8(w0[i], h, a0);
      a1 = dot8(w1[i], h, a1);
      a2 = dot8(w2[i], h, a2);
      a3 = dot8(p3, h, a3);
    }
#pragma unroll
    for (int off = 32; off >= 1; off >>= 1) {
      a0 += __shfl_down(a0, off, 64);
      a1 += __shfl_down(a1, off, 64);
      a2 += __shfl_down(a2, off, 64);
      a3 += __shfl_down(a3, off, 64);
    }
    if (lane == 0) {
      float v0 = tanhf(u0 + a0);
      float v1 = tanhf(u1 + a1);
      float v2 = tanhf(u2 + a2);
      float v3 = tanhf(u3 + a3);
      f16x4 hh;
      hh[0] = (f16)v0; hh[1] = (f16)v1; hh[2] = (f16)v2; hh[3] = (f16)v3;
      *(f16x4*)(h16 + (t & 1) * HDIM + row0) = hh;  // release chain first
      op[0] = v0; op[1] = v1; op[2] = v2; op[3] = v3;
    }
    if (t != NSTEP - 1) gbar(flags, release, (unsigned)(t + 1));
  }
}

// ---------------- fallback path (previous verified kernels) ------------------
__global__ void step0_kernel(float* __restrict__ out) {
  int i = blockIdx.x * blockDim.x + threadIdx.x;
  out[i] = tanhf(out[i]);
}

template <bool WF16>
__global__ __launch_bounds__(1024) void step_kernel(const void* __restrict__ Wv,
                                                    float* __restrict__ out,
                                                    int t) {
  __shared__ typename std::conditional<WF16, f16, float>::type hs[HDIM];
  const float* hprev = out + (size_t)(t - 1) * HDIM;
  {
    const f32x4* hp4 = (const f32x4*)hprev;
    const int tid = threadIdx.x;
#pragma unroll
    for (int i = 0; i < HDIM / 4 / 1024; i++) {
      const int idx = i * 1024 + tid;
      f32x4 v = hp4[idx];
      if constexpr (WF16) {
        f16x4 hh;
        hh[0] = (f16)v[0]; hh[1] = (f16)v[1];
        hh[2] = (f16)v[2]; hh[3] = (f16)v[3];
        *(f16x4*)&hs[idx * 4] = hh;
      } else {
        *(f32x4*)&hs[idx * 4] = v;
      }
    }
  }
  __syncthreads();

  const int wave = threadIdx.x >> 6;
  const int lane = threadIdx.x & 63;
  const int j = blockIdx.x * 16 + wave;
  float acc = 0.f;

  if constexpr (WF16) {
    const f16* wrow = (const f16*)Wv + (size_t)j * HDIM;
#pragma unroll 4
    for (int it = 0; it < 16; it++) {
      const int kb = it * 512 + lane * 8;
      f16x8 w = *(const f16x8*)(wrow + kb);
      f16x8 h = *(const f16x8*)&hs[kb];
      acc = dot2acc(w[0], w[1], h[0], h[1], acc);
      acc = dot2acc(w[2], w[3], h[2], h[3], acc);
      acc = dot2acc(w[4], w[5], h[4], h[5], acc);
      acc = dot2acc(w[6], w[7], h[6], h[7], acc);
    }
  } else {
    const float* wrow = (const float*)Wv + (size_t)j * HDIM;
#pragma unroll 4
    for (int it = 0; it < 16; it++) {
      const int kb = it * 512 + lane * 8;
      f32x4 w0 = *(const f32x4*)(wrow + kb);
      f32x4 w1 = *(const f32x4*)(wrow + kb + 4);
      const float* hp = (const float*)&hs[kb];
      acc += w0[0] * hp[0] + w0[1] * hp[1] + w0[2] * hp[2] + w0[3] * hp[3];
      acc += w1[0] * hp[4] + w1[1] * hp[5] + w1[2] * hp[6] + w1[3] * hp[7];
    }
  }
#pragma unroll
  for (int off = 32; off >= 1; off >>= 1) acc += __shfl_down(acc, off, 64);
  if (lane == 0) {
    const float u = out[(size_t)t * HDIM + j];
    out[(size_t)t * HDIM + j] = tanhf(u + acc);
  }
}

// -----------------------------------------------------------------------------
extern "C" void kernel_launch(void* const* d_in, const int* in_sizes, int n_in,
                              void* d_out, int out_size, void* d_ws,
                              size_t ws_size, hipStream_t stream) {
  const float* x = (const float*)d_in[0];
  const float* Wih = (const float*)d_in[1];
  const float* Whh = (const float*)d_in[2];
  const float* b = (const float*)d_in[3];
  float* out = (float*)d_out;

  // ws layout: [h16 32KiB][flags 64KiB][release][x16 1MiB][w16 128MiB]
  const size_t offH = 0;
  const size_t offFlags = 32 * 1024;
  const size_t offRel = offFlags + NBLK * 128;          // 96 KiB
  const size_t offX = 160 * 1024;
  const size_t offW = offX + (size_t)NSTEP * HDIM * sizeof(f16);  // +1 MiB
  const size_t needFast = offW;                          // ~1.16 MiB
  const size_t needW = (size_t)HDIM * HDIM * sizeof(f16);

  if (ws_size >= needFast) {
    f16* h16 = (f16*)((char*)d_ws + offH);
    unsigned* flags = (unsigned*)((char*)d_ws + offFlags);
    unsigned* release = (unsigned*)((char*)d_ws + offRel);
    f16* x16 = (f16*)((char*)d_ws + offX);

    hipMemsetAsync((char*)d_ws + offFlags, 0, NBLK * 128 + 128, stream);
    cvt_f16_kernel<<<64, 256, 0, stream>>>(x, x16, NSTEP * HDIM / 4);
    gemm_u_kernel<true><<<HDIM / 16, 256, 0, stream>>>(x, x16, Wih, b, out);

    void* args[] = {(void*)&Whh, (void*)&out, (void*)&h16, (void*)&flags,
                    (void*)&release};
    hipError_t rc = hipLaunchCooperativeKernel(
        (void*)rnn_persistent, dim3(NBLK), dim3(256), args, 0, stream);
    if (rc == hipSuccess) return;
    (void)hipGetLastError();  // clear error state, take fallback path

    step0_kernel<<<HDIM / 256, 256, 0, stream>>>(out);
    if (ws_size >= offW + needW) {
      f16* w16 = (f16*)((char*)d_ws + offW);
      cvt_f16_kernel<<<4096, 256, 0, stream>>>(Whh, w16, HDIM * HDIM / 4);
      for (int t = 1; t < NSTEP; t++)
        step_kernel<true><<<HDIM / 16, 1024, 0, stream>>>((const void*)w16, out, t);
    } else {
      for (int t = 1; t < NSTEP; t++)
        step_kernel<false><<<HDIM / 16, 1024, 0, stream>>>((const void*)Whh, out, t);
    }
    return;
  }

  // tiny-workspace fallback: all-fp32 path
  gemm_u_kernel<false><<<HDIM / 16, 256, 0, stream>>>(x, nullptr, Wih, b, out);
  step0_kernel<<<HDIM / 256, 256, 0, stream>>>(out);
  for (int t = 1; t < NSTEP; t++)
    step_kernel<false><<<HDIM / 16, 1024, 0, stream>>>((const void*)Whh, out, t);
}

// Round 5
// 5076.520 us; speedup vs baseline: 1.3119x; 1.0486x over previous
//
#include <hip/hip_runtime.h>
#include <cmath>
#include <type_traits>

// ChEst: shared-weight Elman RNN, H=8192, 64 steps.
//   U = x @ W_ih^T + b   (one f16-MFMA GEMM, written into d_out)
//   h_t = tanh(U[t] + W_hh @ h_{t-1})
// Persistent kernel holds ALL of W_hh on-chip:
//   per wave (2048 waves): rows +0..+2 in 48 NAMED f16x8 SSA values (192 VGPR),
//   row +3 in LDS (16 KiB/wave). Per step: 16 KiB h broadcast + grid barrier.
// R2: cg::grid.sync removed (inlined barrier).  R4 post-mortem: w arrays were
// scratch-allocated at IR level (WRITE_SIZE 99.5MB = 2048 waves x 48KiB
// prologue scratch writes; VGPR=128 was a symptom). Rule-#20 fix: no arrays,
// 48 named variables via macro; h staged to LDS once per block per step.

#define HDIM 8192
#define NSTEP 64
#define NBLK 512

typedef _Float16 f16;
typedef _Float16 f16x2 __attribute__((ext_vector_type(2)));
typedef _Float16 f16x4 __attribute__((ext_vector_type(4)));
typedef _Float16 f16x8 __attribute__((ext_vector_type(8)));
typedef __fp16 fp16x2_raw __attribute__((ext_vector_type(2)));
typedef float f32x4 __attribute__((ext_vector_type(4)));

#if defined(__has_builtin)
#if __has_builtin(__builtin_amdgcn_fdot2)
#define HAS_FDOT2 1
#endif
#endif

__device__ __forceinline__ f16x2 pkrtz(float a, float b) {
  fp16x2_raw r = __builtin_amdgcn_cvt_pkrtz(a, b);
  return __builtin_bit_cast(f16x2, r);
}

__device__ __forceinline__ float dot2acc(f16 a0, f16 a1, f16 b0, f16 b1, float c) {
#ifdef HAS_FDOT2
  f16x2 a = {a0, a1}, b = {b0, b1};
  return __builtin_amdgcn_fdot2(a, b, c, false);
#else
  return c + (float)a0 * (float)b0 + (float)a1 * (float)b1;
#endif
}

__device__ __forceinline__ float dot8(f16x8 a, f16x8 b, float c) {
  c = dot2acc(a[0], a[1], b[0], b[1], c);
  c = dot2acc(a[2], a[3], b[2], b[3], c);
  c = dot2acc(a[4], a[5], b[4], b[5], c);
  c = dot2acc(a[6], a[7], b[6], b[7], c);
  return c;
}

__device__ __forceinline__ f16x8 cvt8(const float* __restrict__ p) {
  f32x4 a0 = *(const f32x4*)p;
  f32x4 a1 = *(const f32x4*)(p + 4);
  f16x2 p0 = pkrtz(a0[0], a0[1]);
  f16x2 p1 = pkrtz(a0[2], a0[3]);
  f16x2 p2 = pkrtz(a1[0], a1[1]);
  f16x2 p3 = pkrtz(a1[2], a1[3]);
  return (f16x8){p0[0], p0[1], p1[0], p1[1], p2[0], p2[1], p3[0], p3[1]};
}

// 16 K-chunks of 512 f16 each (lane covers 8): expand WSTEP(i) for i=0..15.
#define W_FOREACH \
  WSTEP(0) WSTEP(1) WSTEP(2) WSTEP(3) WSTEP(4) WSTEP(5) WSTEP(6) WSTEP(7) \
  WSTEP(8) WSTEP(9) WSTEP(10) WSTEP(11) WSTEP(12) WSTEP(13) WSTEP(14) WSTEP(15)

// ---------------- inlined grid barrier (no external calls) -------------------
// flags[b*32]: arrival epoch of block b (128 B stride). release[0]: go epoch.
// Monotonic epochs, zero-init via hipMemsetAsync each launch -> no ABA.
__device__ __forceinline__ void gbar(unsigned* __restrict__ flags,
                                     unsigned* __restrict__ release,
                                     unsigned e) {
  __threadfence();   // release: make this thread's h16 stores device-visible
  __syncthreads();   // whole block arrived + fenced
  const int tid = threadIdx.x;
  if (blockIdx.x == 0) {
    if (tid == 0)
      __hip_atomic_store(&flags[0], e, __ATOMIC_RELEASE, __HIP_MEMORY_SCOPE_AGENT);
    for (int i = tid; i < NBLK; i += 256) {
      while (__hip_atomic_load(&flags[i * 32], __ATOMIC_RELAXED,
                               __HIP_MEMORY_SCOPE_AGENT) < e)
        __builtin_amdgcn_s_sleep(1);
    }
    __threadfence();  // acquire: order release store after observed arrivals
    __syncthreads();
    if (tid == 0)
      __hip_atomic_store(release, e, __ATOMIC_RELEASE, __HIP_MEMORY_SCOPE_AGENT);
  } else {
    if (tid == 0) {
      __hip_atomic_store(&flags[blockIdx.x * 32], e, __ATOMIC_RELEASE,
                         __HIP_MEMORY_SCOPE_AGENT);
      while (__hip_atomic_load(release, __ATOMIC_RELAXED,
                               __HIP_MEMORY_SCOPE_AGENT) < e)
        __builtin_amdgcn_s_sleep(1);
    }
    __syncthreads();
  }
  __threadfence();   // acquire side: drop stale cached h16 lines
}

// ---------------- fp32 -> fp16 convert (grid-stride, vectorized) -------------
__global__ void cvt_f16_kernel(const float* __restrict__ src,
                               f16* __restrict__ dst, int n4) {
  int idx = blockIdx.x * blockDim.x + threadIdx.x;
  int stride = gridDim.x * blockDim.x;
  for (int i = idx; i < n4; i += stride) {
    f32x4 v = ((const f32x4*)src)[i];
    f16x4 h;
    h[0] = (f16)v[0]; h[1] = (f16)v[1]; h[2] = (f16)v[2]; h[3] = (f16)v[3];
    ((f16x4*)dst)[i] = h;
  }
}

// ---------------- Phase 1: U = x @ W_ih^T + b  (into d_out) ------------------
template <bool XF16>
__global__ __launch_bounds__(256) void gemm_u_kernel(
    const float* __restrict__ x, const f16* __restrict__ x16,
    const float* __restrict__ Wih, const float* __restrict__ b,
    float* __restrict__ out) {
  const int wave = threadIdx.x >> 6;
  const int lane = threadIdx.x & 63;
  const int r = lane & 15, q = lane >> 4;
  const int n0 = blockIdx.x * 16;
  const int m0 = wave * 16;
  const float* wrow = Wih + (size_t)(n0 + r) * HDIM;
  f32x4 acc = {0.f, 0.f, 0.f, 0.f};
#pragma unroll 2
  for (int k0 = 0; k0 < HDIM; k0 += 32) {
    const int kb = k0 + q * 8;
    f16x8 fa;
    if constexpr (XF16) {
      fa = *(const f16x8*)(x16 + (size_t)(m0 + r) * HDIM + kb);
    } else {
      f32x4 a0 = *(const f32x4*)(x + (size_t)(m0 + r) * HDIM + kb);
      f32x4 a1 = *(const f32x4*)(x + (size_t)(m0 + r) * HDIM + kb + 4);
      f16x2 p0 = pkrtz(a0[0], a0[1]);
      f16x2 p1 = pkrtz(a0[2], a0[3]);
      f16x2 p2 = pkrtz(a1[0], a1[1]);
      f16x2 p3 = pkrtz(a1[2], a1[3]);
      fa = (f16x8){p0[0], p0[1], p1[0], p1[1], p2[0], p2[1], p3[0], p3[1]};
    }
    f32x4 b0 = *(const f32x4*)(wrow + kb);
    f32x4 b1 = *(const f32x4*)(wrow + kb + 4);
    f16x2 q0 = pkrtz(b0[0], b0[1]);
    f16x2 q1 = pkrtz(b0[2], b0[3]);
    f16x2 q2 = pkrtz(b1[0], b1[1]);
    f16x2 q3 = pkrtz(b1[2], b1[3]);
    f16x8 fb = {q0[0], q0[1], q1[0], q1[1], q2[0], q2[1], q3[0], q3[1]};
    acc = __builtin_amdgcn_mfma_f32_16x16x32_f16(fa, fb, acc, 0, 0, 0);
  }
  const float bv = b[n0 + r];
#pragma unroll
  for (int i = 0; i < 4; i++) {
    out[(size_t)(m0 + q * 4 + i) * HDIM + n0 + r] = acc[i] + bv;
  }
}

// ---------------- persistent RNN (all 64 steps, manual grid barrier) ---------
// grid = 512 blocks x 256 thr (4 waves). Global wave gw owns rows 4*gw..+3:
// rows +0,+1,+2 in named VGPR values (192), row +3 in wlds. h staged in hlds.
// LDS 64+16=80 KiB -> exactly 2 blocks/CU. waves_per_eu(2,2) -> 256-reg/wave.
__global__ __attribute__((amdgpu_flat_work_group_size(256, 256)))
__attribute__((amdgpu_waves_per_eu(2, 2))) void rnn_persistent(
    const float* __restrict__ Whh, float* __restrict__ out,
    f16* __restrict__ h16, unsigned* __restrict__ flags,
    unsigned* __restrict__ release) {
  __shared__ f16 wlds[4][HDIM];  // 64 KiB: 4th W row per wave
  __shared__ f16 hlds[HDIM];     // 16 KiB: h_{t-1} staged per block
  const int wave = threadIdx.x >> 6;
  const int lane = threadIdx.x & 63;
  const int row0 = (blockIdx.x * 4 + wave) * 4;
  const int lb = lane * 8;

  // ---- 48 named W values: no allocas, nothing for SROA to miss ----
#define WSTEP(i) f16x8 w0_##i, w1_##i, w2_##i;
  W_FOREACH
#undef WSTEP

  // ---- prologue: load + convert W_hh rows once (fp32 -> fp16) ----
#define WSTEP(i) {                                      \
    const int kb = (i) * 512 + lb;                      \
    const float* p = Whh + (size_t)row0 * HDIM + kb;    \
    w0_##i = cvt8(p);                                   \
    w1_##i = cvt8(p + HDIM);                            \
    w2_##i = cvt8(p + 2 * HDIM);                        \
    *(f16x8*)&wlds[wave][kb] = cvt8(p + 3 * HDIM); }
  W_FOREACH
#undef WSTEP

  // ---- step 0: h_0 = tanh(U[0]) (h_init = 0) ----
  if (lane < 4) {
    float v = tanhf(out[row0 + lane]);
    h16[row0 + lane] = (f16)v;  // buffer 0 first: readers wait on this
    out[row0 + lane] = v;
  }
  gbar(flags, release, 1u);

  for (int t = 1; t < NSTEP; t++) {
    // ---- stage h_{t-1} into LDS: one global round-trip per block ----
    {
      const f16* hp = h16 + ((t - 1) & 1) * HDIM;
      const int tid = threadIdx.x;
#pragma unroll
      for (int i = 0; i < 4; i++) {
        const int idx = (i * 256 + tid) * 8;
        *(f16x8*)&hlds[idx] = *(const f16x8*)(hp + idx);
      }
    }
    // Prefetch U[t] for this wave's rows (hidden under staging + dot loop).
    float* op = out + (size_t)t * HDIM + row0;
    float u0, u1, u2, u3;
    if (lane == 0) { u0 = op[0]; u1 = op[1]; u2 = op[2]; u3 = op[3]; }
    __syncthreads();

    float a0 = 0.f, a1 = 0.f, a2 = 0.f, a3 = 0.f;
#define WSTEP(i) {                                      \
    const int kb = (i) * 512 + lb;                      \
    f16x8 h = *(const f16x8*)&hlds[kb];                 \
    f16x8 p3 = *(const f16x8*)&wlds[wave][kb];          \
    a0 = dot8(w0_##i, h, a0);                           \
    a1 = dot8(w1_##i, h, a1);                           \
    a2 = dot8(w2_##i, h, a2);                           \
    a3 = dot8(p3, h, a3); }
    W_FOREACH
#undef WSTEP

#pragma unroll
    for (int off = 32; off >= 1; off >>= 1) {
      a0 += __shfl_down(a0, off, 64);
      a1 += __shfl_down(a1, off, 64);
      a2 += __shfl_down(a2, off, 64);
      a3 += __shfl_down(a3, off, 64);
    }
    if (lane == 0) {
      float v0 = tanhf(u0 + a0);
      float v1 = tanhf(u1 + a1);
      float v2 = tanhf(u2 + a2);
      float v3 = tanhf(u3 + a3);
      f16x4 hh;
      hh[0] = (f16)v0; hh[1] = (f16)v1; hh[2] = (f16)v2; hh[3] = (f16)v3;
      *(f16x4*)(h16 + (t & 1) * HDIM + row0) = hh;  // release chain first
      op[0] = v0; op[1] = v1; op[2] = v2; op[3] = v3;
    }
    if (t != NSTEP - 1) gbar(flags, release, (unsigned)(t + 1));
  }
}

// ---------------- fallback path (previous verified kernels) ------------------
__global__ void step0_kernel(float* __restrict__ out) {
  int i = blockIdx.x * blockDim.x + threadIdx.x;
  out[i] = tanhf(out[i]);
}

template <bool WF16>
__global__ __launch_bounds__(1024) void step_kernel(const void* __restrict__ Wv,
                                                    float* __restrict__ out,
                                                    int t) {
  __shared__ typename std::conditional<WF16, f16, float>::type hs[HDIM];
  const float* hprev = out + (size_t)(t - 1) * HDIM;
  {
    const f32x4* hp4 = (const f32x4*)hprev;
    const int tid = threadIdx.x;
#pragma unroll
    for (int i = 0; i < HDIM / 4 / 1024; i++) {
      const int idx = i * 1024 + tid;
      f32x4 v = hp4[idx];
      if constexpr (WF16) {
        f16x4 hh;
        hh[0] = (f16)v[0]; hh[1] = (f16)v[1];
        hh[2] = (f16)v[2]; hh[3] = (f16)v[3];
        *(f16x4*)&hs[idx * 4] = hh;
      } else {
        *(f32x4*)&hs[idx * 4] = v;
      }
    }
  }
  __syncthreads();

  const int wave = threadIdx.x >> 6;
  const int lane = threadIdx.x & 63;
  const int j = blockIdx.x * 16 + wave;
  float acc = 0.f;

  if constexpr (WF16) {
    const f16* wrow = (const f16*)Wv + (size_t)j * HDIM;
#pragma unroll 4
    for (int it = 0; it < 16; it++) {
      const int kb = it * 512 + lane * 8;
      f16x8 w = *(const f16x8*)(wrow + kb);
      f16x8 h = *(const f16x8*)&hs[kb];
      acc = dot2acc(w[0], w[1], h[0], h[1], acc);
      acc = dot2acc(w[2], w[3], h[2], h[3], acc);
      acc = dot2acc(w[4], w[5], h[4], h[5], acc);
      acc = dot2acc(w[6], w[7], h[6], h[7], acc);
    }
  } else {
    const float* wrow = (const float*)Wv + (size_t)j * HDIM;
#pragma unroll 4
    for (int it = 0; it < 16; it++) {
      const int kb = it * 512 + lane * 8;
      f32x4 w0 = *(const f32x4*)(wrow + kb);
      f32x4 w1 = *(const f32x4*)(wrow + kb + 4);
      const float* hp = (const float*)&hs[kb];
      acc += w0[0] * hp[0] + w0[1] * hp[1] + w0[2] * hp[2] + w0[3] * hp[3];
      acc += w1[0] * hp[4] + w1[1] * hp[5] + w1[2] * hp[6] + w1[3] * hp[7];
    }
  }
#pragma unroll
  for (int off = 32; off >= 1; off >>= 1) acc += __shfl_down(acc, off, 64);
  if (lane == 0) {
    const float u = out[(size_t)t * HDIM + j];
    out[(size_t)t * HDIM + j] = tanhf(u + acc);
  }
}

// -----------------------------------------------------------------------------
extern "C" void kernel_launch(void* const* d_in, const int* in_sizes, int n_in,
                              void* d_out, int out_size, void* d_ws,
                              size_t ws_size, hipStream_t stream) {
  const float* x = (const float*)d_in[0];
  const float* Wih = (const float*)d_in[1];
  const float* Whh = (const float*)d_in[2];
  const float* b = (const float*)d_in[3];
  float* out = (float*)d_out;

  // ws layout: [h16 32KiB][flags 64KiB][release][x16 1MiB][w16 128MiB]
  const size_t offH = 0;
  const size_t offFlags = 32 * 1024;
  const size_t offRel = offFlags + NBLK * 128;          // 96 KiB
  const size_t offX = 160 * 1024;
  const size_t offW = offX + (size_t)NSTEP * HDIM * sizeof(f16);  // +1 MiB
  const size_t needFast = offW;                          // ~1.16 MiB
  const size_t needW = (size_t)HDIM * HDIM * sizeof(f16);

  if (ws_size >= needFast) {
    f16* h16 = (f16*)((char*)d_ws + offH);
    unsigned* flags = (unsigned*)((char*)d_ws + offFlags);
    unsigned* release = (unsigned*)((char*)d_ws + offRel);
    f16* x16 = (f16*)((char*)d_ws + offX);

    hipMemsetAsync((char*)d_ws + offFlags, 0, NBLK * 128 + 128, stream);
    cvt_f16_kernel<<<64, 256, 0, stream>>>(x, x16, NSTEP * HDIM / 4);
    gemm_u_kernel<true><<<HDIM / 16, 256, 0, stream>>>(x, x16, Wih, b, out);

    void* args[] = {(void*)&Whh, (void*)&out, (void*)&h16, (void*)&flags,
                    (void*)&release};
    hipError_t rc = hipLaunchCooperativeKernel(
        (void*)rnn_persistent, dim3(NBLK), dim3(256), args, 0, stream);
    if (rc == hipSuccess) return;
    (void)hipGetLastError();  // clear error state, take fallback path

    step0_kernel<<<HDIM / 256, 256, 0, stream>>>(out);
    if (ws_size >= offW + needW) {
      f16* w16 = (f16*)((char*)d_ws + offW);
      cvt_f16_kernel<<<4096, 256, 0, stream>>>(Whh, w16, HDIM * HDIM / 4);
      for (int t = 1; t < NSTEP; t++)
        step_kernel<true><<<HDIM / 16, 1024, 0, stream>>>((const void*)w16, out, t);
    } else {
      for (int t = 1; t < NSTEP; t++)
        step_kernel<false><<<HDIM / 16, 1024, 0, stream>>>((const void*)Whh, out, t);
    }
    return;
  }

  // tiny-workspace fallback: all-fp32 path
  gemm_u_kernel<false><<<HDIM / 16, 256, 0, stream>>>(x, nullptr, Wih, b, out);
  step0_kernel<<<HDIM / 256, 256, 0, stream>>>(out);
  for (int t = 1; t < NSTEP; t++)
    step_kernel<false><<<HDIM / 16, 1024, 0, stream>>>((const void*)Whh, out, t);
}